// Round 9
// baseline (583.862 us; speedup 1.0000x reference)
//
#include <hip/hip_runtime.h>
#include <math.h>

// Soft-Viterbi structured decoding: B=32, T=512, N=128, fp32.
// Round-9: TWO batch elements per block via ILP IN ONE WAVE (16 blocks x
// 256 threads). Round-8 showed TLP (2 waves/SIMD, 8-wave barrier) adds
// more skew than it hides; here each lane carries two independent
// register dataflows (elements A,B) through the SAME instruction stream:
// the second dot chain issues during the first's LDS/DPP stall cycles.
// Transition fragments tf2/tb2 are shared (same matrix) — only live
// per-element state doubles. Barrier still syncs only 4 waves.
// Per-wave step structure identical to round 6 (pk-FMA dot, DPP quad
// combine, rcp scale factors, depth-4 em rings, LDS-only barrier).

#define TT 512
#define BB 32
#define NN 128
#define EPSC 1e-10f
#define TINY 1e-33f

typedef float v2f __attribute__((ext_vector_type(2)));

// Fused LDS-drain + barrier. No vmcnt wait (global ops stay in flight).
#define BAR() asm volatile("s_waitcnt lgkmcnt(0)\n\ts_barrier" ::: "memory")

__device__ __forceinline__ float rcp_fast(float x) {
  return __builtin_amdgcn_rcpf(x);
}
__device__ __forceinline__ float qswap1(float x) {
  return __int_as_float(__builtin_amdgcn_mov_dpp(__float_as_int(x), 0xB1, 0xF, 0xF, true));
}
__device__ __forceinline__ float qswap2(float x) {
  return __int_as_float(__builtin_amdgcn_mov_dpp(__float_as_int(x), 0x4E, 0xF, 0xF, true));
}

// 32-element partial dot via 16 packed FMAs (4 independent chains).
__device__ __forceinline__ float dotpk16(const v2f* av, const v2f tm[16]) {
  v2f a0 = av[0] * tm[0];
  v2f a1 = av[1] * tm[1];
  v2f a2 = av[2] * tm[2];
  v2f a3 = av[3] * tm[3];
  #pragma unroll
  for (int j = 4; j < 16; j += 4) {
    a0 = __builtin_elementwise_fma(av[j+0], tm[j+0], a0);
    a1 = __builtin_elementwise_fma(av[j+1], tm[j+1], a1);
    a2 = __builtin_elementwise_fma(av[j+2], tm[j+2], a2);
    a3 = __builtin_elementwise_fma(av[j+3], tm[j+3], a3);
  }
  v2f s = (a0 + a1) + (a2 + a3);
  return s.x + s.y;
}

__global__ __launch_bounds__(256, 1)
void soft_viterbi_kernel(const float* __restrict__ trans,
                         const float* __restrict__ emis,
                         const float* __restrict__ prior,
                         float* __restrict__ out) {
  const int tid  = threadIdx.x;
  const int w    = tid >> 6;
  const int lane = tid & 63;
  const int k    = lane & 3;             // k-chunk within quad
  const int pid  = lane >> 2;            // state-pair id within wave (0..15)
  const int n0   = 32 * w + 2 * pid;     // first owned state (2 per lane)
  const int bA   = 2 * blockIdx.x;       // element A
  const int bB   = bA + 1;               // element B

  __shared__ __align__(16) float ubuf[2][2][NN];  // [elem][pingpong] exchange
  __shared__ __align__(16) float sarr[2][TT];     // [elem] 1/alpha~_t[0]
  __shared__ __align__(16) float red[NN];         // transition row sums
  __shared__ float rsc[2][4];                     // [elem] reduction scratch

  const float* emA = emis + (size_t)bA * TT * NN;
  const float* emBp = emis + (size_t)bB * TT * NN;
  float* outA = out + (size_t)bA * TT * NN;
  float* outB = out + (size_t)bB * TT * NN;

  // ---- issue early global loads (prior shared; em[0..5] per element) ----
  float2 pr2 = *(const float2*)(prior + n0);
  float2 em0A = *(const float2*)(emA + n0);
  float2 em0B = *(const float2*)(emBp + n0);
  float2 e1A = *(const float2*)(emA + 1 * NN + n0);
  float2 e1B = *(const float2*)(emBp + 1 * NN + n0);
  float2 e2A = *(const float2*)(emA + 2 * NN + n0);
  float2 e2B = *(const float2*)(emBp + 2 * NN + n0);
  float2 e3A = *(const float2*)(emA + 3 * NN + n0);
  float2 e3B = *(const float2*)(emBp + 3 * NN + n0);
  float2 e4A = *(const float2*)(emA + 4 * NN + n0);
  float2 e4B = *(const float2*)(emBp + 4 * NN + n0);
  float2 e5A = *(const float2*)(emA + 5 * NN + n0);
  float2 e5B = *(const float2*)(emBp + 5 * NN + n0);
  pr2.x = fmaxf(pr2.x, EPSC); pr2.y = fmaxf(pr2.y, EPSC);

  // ---- row sums of clipped transition ----
  if (tid < NN) {
    const float4* row = (const float4*)(trans + tid * NN);
    float s = 0.f;
    #pragma unroll 8
    for (int j = 0; j < NN / 4; ++j) {
      float4 v = row[j];
      s += fmaxf(v.x, EPSC) + fmaxf(v.y, EPSC) + fmaxf(v.z, EPSC) + fmaxf(v.w, EPSC);
    }
    red[tid] = s;
  }
  __syncthreads();

  // ---- forward fragment (shared): tf2[s][2i+(c>>1)][c&1] = Tn[p][n0+s], p=4(k+4i)+c ----
  v2f tf2[2][16];
  #pragma unroll
  for (int i = 0; i < 8; ++i) {
    #pragma unroll
    for (int c = 0; c < 4; ++c) {
      const int p = 4 * (k + 4 * i) + c;
      const float2 tv = *(const float2*)(trans + p * NN + n0);
      const float rp = red[p];
      tf2[0][2*i + (c >> 1)][c & 1] = fmaxf(tv.x, EPSC) / rp;
      tf2[1][2*i + (c >> 1)][c & 1] = fmaxf(tv.y, EPSC) / rp;
    }
  }
  // ---- backward fragment (shared): tb2[s][...] = Tn[n0+s][4(k+4i)+c] ----
  v2f tb2[2][16];
  #pragma unroll
  for (int s = 0; s < 2; ++s) {
    const float inv = 1.0f / red[n0 + s];
    const float4* rr = (const float4*)(trans + (n0 + s) * NN);
    #pragma unroll
    for (int i = 0; i < 8; ++i) {
      const float4 tv = rr[k + 4 * i];
      tb2[s][2*i+0][0] = fmaxf(tv.x, EPSC) * inv;
      tb2[s][2*i+0][1] = fmaxf(tv.y, EPSC) * inv;
      tb2[s][2*i+1][0] = fmaxf(tv.z, EPSC) * inv;
      tb2[s][2*i+1][1] = fmaxf(tv.w, EPSC) * inv;
    }
  }

  // ---- prior normalization (prior shared -> same psum for A and B) ----
  float vv = (k == 0) ? (pr2.x + pr2.y) : 0.f;
  #pragma unroll
  for (int m = 1; m < 64; m <<= 1) vv += __shfl_xor(vv, m, 64);
  __syncthreads();                 // all tf/tb reads of red[] complete
  if (lane == 0) rsc[0][w] = vv;
  __syncthreads();
  const float psum = (rsc[0][0] + rsc[0][1]) + (rsc[0][2] + rsc[0][3]);
  const float ip0 = pr2.x / psum, ip1 = pr2.y / psum;

  // ---- u0 = alpha~_0 (both elements) ----
  float anA0 = ip0 * __expf(em0A.x), anA1 = ip1 * __expf(em0A.y);
  float anB0 = ip0 * __expf(em0B.x), anB1 = ip1 * __expf(em0B.y);
  if (k == 0) {
    *(float2*)&ubuf[0][0][n0] = make_float2(anA0, anA1);
    *(float2*)&ubuf[1][0][n0] = make_float2(anB0, anB1);
    *(float2*)(outA + n0) = make_float2(anA0, anA1);
    *(float2*)(outB + n0) = make_float2(anB0, anB1);
  }
  float dcA0 = __expf(e1A.x), dcA1 = __expf(e1A.y);  // d_1
  float dcB0 = __expf(e1B.x), dcB1 = __expf(e1B.y);
  // Emission rings: slot m&3 holds em[m]; entering step t slots hold em[t+1..t+4].
  float2 rgA0 = e4A, rgA1 = e5A, rgA2 = e2A, rgA3 = e3A;
  float2 rgB0 = e4B, rgB1 = e5B, rgB2 = e2B, rgB3 = e3B;
  BAR();                           // publish ubuf[*][0]

  // ================= forward =================
  // Invariant entering step t: dc = d_t; slot (t+1)&3 holds em[t+1].
  auto fstep = [&](int pp, int t, float2& slotA, float2& slotB) {
    const float* rbA = ubuf[0][pp];
    const float* rbB = ubuf[1][pp];
    float* wbA = ubuf[0][pp ^ 1];
    float* wbB = ubuf[1][pp ^ 1];
    const float r0A = rbA[0];                     // broadcast reads, land early
    const float r0B = rbB[0];
    const float4* rb4A = (const float4*)rbA;
    const float4* rb4B = (const float4*)rbB;
    float4 a4A[8], a4B[8];
    #pragma unroll
    for (int i = 0; i < 8; ++i) { a4A[i] = rb4A[k + 4 * i]; a4B[i] = rb4B[k + 4 * i]; }
    const v2f* avA = (const v2f*)a4A;
    const v2f* avB = (const v2f*)a4B;
    float zA0 = dotpk16(avA, tf2[0]);
    float zB0 = dotpk16(avB, tf2[0]);
    float zA1 = dotpk16(avA, tf2[1]);
    float zB1 = dotpk16(avB, tf2[1]);
    zA0 += qswap1(zA0); zB0 += qswap1(zB0);
    zA1 += qswap1(zA1); zB1 += qswap1(zB1);
    zA0 += qswap2(zA0); zB0 += qswap2(zB0);
    zA1 += qswap2(zA1); zB1 += qswap2(zB1);
    const float rinvA = rcp_fast(r0A);
    const float rinvB = rcp_fast(r0B);
    anA0 = (dcA0 * rinvA) * zA0;  anA1 = (dcA1 * rinvA) * zA1;
    anB0 = (dcB0 * rinvB) * zB0;  anB1 = (dcB1 * rinvB) * zB1;
    dcA0 = __expf(slotA.x); dcA1 = __expf(slotA.y);   // d_{t+1}, off-chain
    dcB0 = __expf(slotB.x); dcB1 = __expf(slotB.y);
    const int tpre = (t + 5 < TT) ? (t + 5) : (TT - 1);
    slotA = *(const float2*)(emA  + (size_t)tpre * NN + n0);  // em[t+5]
    slotB = *(const float2*)(emBp + (size_t)tpre * NN + n0);
    if (k == 0) {
      *(float2*)(wbA + n0) = make_float2(anA0, anA1);
      *(float2*)(wbB + n0) = make_float2(anB0, anB1);
      if (t < TT - 1) {
        *(float2*)(outA + (size_t)t * NN + n0) = make_float2(anA0, anA1);
        *(float2*)(outB + (size_t)t * NN + n0) = make_float2(anB0, anB1);
      }
    }
    if (tid == 0) { sarr[0][t - 1] = rinvA; sarr[1][t - 1] = rinvB; }
    BAR();
  };

  fstep(0, 1, rgA2, rgB2);                        // peel t=1,2,3
  fstep(1, 2, rgA3, rgB3);
  fstep(0, 3, rgA0, rgB0);
  for (int t = 4; t < TT; t += 4) {
    fstep(1, t + 0, rgA1, rgB1);
    fstep(0, t + 1, rgA2, rgB2);
    fstep(1, t + 2, rgA3, rgB3);
    fstep(0, t + 3, rgA0, rgB0);
  }
  const float dlA0 = dcA0, dlA1 = dcA1;           // = d_{T-1} (clamped rings)
  const float dlB0 = dcB0, dlB1 = dcB1;

  // ================= final softmax (both elements) =================
  float vA = (k == 0) ? (anA0 + anA1) : 0.f;
  float vB = (k == 0) ? (anB0 + anB1) : 0.f;
  #pragma unroll
  for (int m = 1; m < 64; m <<= 1) { vA += __shfl_xor(vA, m, 64); vB += __shfl_xor(vB, m, 64); }
  if (lane == 0) { rsc[0][w] = vA; rsc[1][w] = vB; }
  __syncthreads();
  const float itotA = 1.0f / ((rsc[0][0] + rsc[0][1]) + (rsc[0][2] + rsc[0][3]));
  const float itotB = 1.0f / ((rsc[1][0] + rsc[1][1]) + (rsc[1][2] + rsc[1][3]));
  float pcA0 = anA0 * itotA, pcA1 = anA1 * itotA;
  float pcB0 = anB0 * itotB, pcB1 = anB1 * itotB;
  if (k == 0) {
    *(float2*)(outA + (size_t)(TT - 1) * NN + n0) = make_float2(pcA0, pcA1);
    *(float2*)(outB + (size_t)(TT - 1) * NN + n0) = make_float2(pcB0, pcB1);
  }

  // One-time drain: forward alpha-stash stores must be visible before the
  // backward pass re-reads them (same-wave vmem ops are not address-ordered).
  asm volatile("s_waitcnt vmcnt(0)" ::: "memory");

  // ---- backward rings: slot m&3 holds em[m] / alpha~[m] ----
  float2 ebA2 = *(const float2*)(emA  + (size_t)510 * NN + n0);
  float2 ebB2 = *(const float2*)(emBp + (size_t)510 * NN + n0);
  float2 ebA1 = *(const float2*)(emA  + (size_t)509 * NN + n0);
  float2 ebB1 = *(const float2*)(emBp + (size_t)509 * NN + n0);
  float2 ebA0 = *(const float2*)(emA  + (size_t)508 * NN + n0);
  float2 ebB0 = *(const float2*)(emBp + (size_t)508 * NN + n0);
  float2 ebA3 = *(const float2*)(emA  + (size_t)507 * NN + n0);
  float2 ebB3 = *(const float2*)(emBp + (size_t)507 * NN + n0);
  float2 acA2 = *(const float2*)(outA + (size_t)510 * NN + n0);
  float2 acB2 = *(const float2*)(outB + (size_t)510 * NN + n0);
  float2 acA1 = *(const float2*)(outA + (size_t)509 * NN + n0);
  float2 acB1 = *(const float2*)(outB + (size_t)509 * NN + n0);
  float2 acA0 = *(const float2*)(outA + (size_t)508 * NN + n0);
  float2 acB0 = *(const float2*)(outB + (size_t)508 * NN + n0);
  float2 acA3 = *(const float2*)(outA + (size_t)507 * NN + n0);
  float2 acB3 = *(const float2*)(outB + (size_t)507 * NN + n0);
  const float slA = sarr[0][TT - 2];
  const float slB = sarr[1][TT - 2];
  float gA0 = dlA0 * slA * rcp_fast(fmaxf(anA0, TINY));  // g_{T-2}
  float gA1 = dlA1 * slA * rcp_fast(fmaxf(anA1, TINY));
  float gB0 = dlB0 * slB * rcp_fast(fmaxf(anB0, TINY));
  float gB1 = dlB1 * slB * rcp_fast(fmaxf(anB1, TINY));

  // ================= backward =================
  // Invariant entering step t: pc = p_{t+1}, g = g_t, em-slot t&3 = em[t],
  // ec-slot t&3 = alpha~_t.
  auto bstep = [&](int pp, int t, float2& emsA, float2& ecsA, float2& emsB, float2& ecsB) {
    float* xbA = ubuf[0][pp];
    float* xbB = ubuf[1][pp];
    if (k == 0) {
      *(float2*)(xbA + n0) = make_float2(pcA0 * gA0, pcA1 * gA1);   // q_t
      *(float2*)(xbB + n0) = make_float2(pcB0 * gB0, pcB1 * gB1);
    }
    const float srA = sarr[0][(t > 0) ? (t - 1) : 0];
    const float srB = sarr[1][(t > 0) ? (t - 1) : 0];
    const float atA0 = ecsA.x, atA1 = ecsA.y;     // alpha~_t
    const float atB0 = ecsB.x, atB1 = ecsB.y;
    const float gnA0 = __expf(emsA.x) * srA * rcp_fast(fmaxf(atA0, TINY));
    const float gnA1 = __expf(emsA.y) * srA * rcp_fast(fmaxf(atA1, TINY));
    const float gnB0 = __expf(emsB.x) * srB * rcp_fast(fmaxf(atB0, TINY));
    const float gnB1 = __expf(emsB.y) * srB * rcp_fast(fmaxf(atB1, TINY));
    const int tp4 = (t >= 4) ? (t - 4) : 0;
    emsA = *(const float2*)(emA  + (size_t)tp4 * NN + n0);   // em[t-4]
    emsB = *(const float2*)(emBp + (size_t)tp4 * NN + n0);
    ecsA = *(const float2*)(outA + (size_t)tp4 * NN + n0);   // alpha~[t-4]
    ecsB = *(const float2*)(outB + (size_t)tp4 * NN + n0);
    BAR();
    const float4* qb4A = (const float4*)xbA;
    const float4* qb4B = (const float4*)xbB;
    float4 a4A[8], a4B[8];
    #pragma unroll
    for (int i = 0; i < 8; ++i) { a4A[i] = qb4A[k + 4 * i]; a4B[i] = qb4B[k + 4 * i]; }
    const v2f* avA = (const v2f*)a4A;
    const v2f* avB = (const v2f*)a4B;
    float zA0 = dotpk16(avA, tb2[0]);
    float zB0 = dotpk16(avB, tb2[0]);
    float zA1 = dotpk16(avA, tb2[1]);
    float zB1 = dotpk16(avB, tb2[1]);
    zA0 += qswap1(zA0); zB0 += qswap1(zB0);
    zA1 += qswap1(zA1); zB1 += qswap1(zB1);
    zA0 += qswap2(zA0); zB0 += qswap2(zB0);
    zA1 += qswap2(zA1); zB1 += qswap2(zB1);
    pcA0 = atA0 * zA0;  pcA1 = atA1 * zA1;        // p_t
    pcB0 = atB0 * zB0;  pcB1 = atB1 * zB1;
    if (k == 0) {
      *(float2*)(outA + (size_t)t * NN + n0) = make_float2(pcA0, pcA1);
      *(float2*)(outB + (size_t)t * NN + n0) = make_float2(pcB0, pcB1);
    }
    gA0 = gnA0; gA1 = gnA1; gB0 = gnB0; gB1 = gnB1;
  };

  bstep(0, 510, ebA2, acA2, ebB2, acB2);          // peel t=510,509,508
  bstep(1, 509, ebA1, acA1, ebB1, acB1);
  bstep(0, 508, ebA0, acA0, ebB0, acB0);
  for (int t = 507; t >= 3; t -= 4) {
    bstep(1, t - 0, ebA3, acA3, ebB3, acB3);
    bstep(0, t - 1, ebA2, acA2, ebB2, acB2);
    bstep(1, t - 2, ebA1, acA1, ebB1, acB1);
    bstep(0, t - 3, ebA0, acA0, ebB0, acB0);
  }
}

extern "C" void kernel_launch(void* const* d_in, const int* in_sizes, int n_in,
                              void* d_out, int out_size, void* d_ws, size_t ws_size,
                              hipStream_t stream) {
  (void)in_sizes; (void)n_in; (void)d_ws; (void)ws_size; (void)out_size;
  const float* trans = (const float*)d_in[0];
  const float* emis  = (const float*)d_in[1];
  const float* prior = (const float*)d_in[2];
  float* out = (float*)d_out;
  soft_viterbi_kernel<<<dim3(BB / 2), dim3(256), 0, stream>>>(trans, emis, prior, out);
}

// Round 10
// 399.962 us; speedup vs baseline: 1.4598x; 1.4598x over previous
//
#include <hip/hip_runtime.h>
#include <math.h>

// Soft-Viterbi structured decoding: B=32, T=512, N=128, fp32.
// Linear-space formulation, ONE barrier + ONE LDS round trip per step.
//
// FINAL (round-6 structure, reverted after rounds 7-9 falsified all
// latency-fill alternatives: 1-wave/elem = issue-bound 871us; 2-elem TLP
// shared barrier = skew-bound 452us; 2-elem ILP = DS-serialization 537us).
// Per-step chain: LDS round-trip + 4-wave barrier + ~140cy VALU issue.
//  * 4 waves, 256 threads; lane k=lane&3 sums K-granules k+4i
//    (16-way broadcast, zero bank conflicts), 2 states/lane.
//  * v_pk_fma_f32 packed dot (16 pk-FMA per 32-elem chunk).
//  * DPP quad_perm combine (pure VALU, no DS ops on chain).
//  * v_rcp_f32 for all per-step scale factors (consistent-scale safe).
//  * LDS-only barrier (s_waitcnt lgkmcnt(0); s_barrier) — global stores
//    and em prefetches stay in flight across steps.
//  * Depth-4 register rings for streamed em/alpha operands.

#define TT 512
#define BB 32
#define NN 128
#define EPSC 1e-10f
#define TINY 1e-33f

typedef float v2f __attribute__((ext_vector_type(2)));

// Fused LDS-drain + barrier. No vmcnt wait (global ops stay in flight).
#define BAR() asm volatile("s_waitcnt lgkmcnt(0)\n\ts_barrier" ::: "memory")

// Single-instruction v_rcp_f32 (~1ulp). Used only for scale factors where
// exactness is irrelevant (consistent-scale normalization).
__device__ __forceinline__ float rcp_fast(float x) {
  return __builtin_amdgcn_rcpf(x);
}

// DPP quad_perm lane swaps (xor 1 / xor 2 within each 4-lane quad).
__device__ __forceinline__ float qswap1(float x) {
  return __int_as_float(__builtin_amdgcn_mov_dpp(__float_as_int(x), 0xB1, 0xF, 0xF, true));
}
__device__ __forceinline__ float qswap2(float x) {
  return __int_as_float(__builtin_amdgcn_mov_dpp(__float_as_int(x), 0x4E, 0xF, 0xF, true));
}

// 32-element partial dot via 16 packed FMAs (4 independent chains).
__device__ __forceinline__ float dotpk16(const v2f* av, const v2f tm[16]) {
  v2f a0 = av[0] * tm[0];
  v2f a1 = av[1] * tm[1];
  v2f a2 = av[2] * tm[2];
  v2f a3 = av[3] * tm[3];
  #pragma unroll
  for (int j = 4; j < 16; j += 4) {
    a0 = __builtin_elementwise_fma(av[j+0], tm[j+0], a0);
    a1 = __builtin_elementwise_fma(av[j+1], tm[j+1], a1);
    a2 = __builtin_elementwise_fma(av[j+2], tm[j+2], a2);
    a3 = __builtin_elementwise_fma(av[j+3], tm[j+3], a3);
  }
  v2f s = (a0 + a1) + (a2 + a3);
  return s.x + s.y;
}

__global__ __launch_bounds__(256, 1)
void soft_viterbi_kernel(const float* __restrict__ trans,
                         const float* __restrict__ emis,
                         const float* __restrict__ prior,
                         float* __restrict__ out) {
  const int b    = blockIdx.x;
  const int tid  = threadIdx.x;
  const int w    = tid >> 6;
  const int lane = tid & 63;
  const int k    = lane & 3;             // k-chunk within quad
  const int pid  = lane >> 2;            // state-pair id within wave (0..15)
  const int n0   = 32 * w + 2 * pid;     // first owned state (2 per lane)

  __shared__ __align__(16) float ubuf[2][NN];  // ping-pong alpha~ / q exchange
  __shared__ __align__(16) float sarr[TT];     // sarr[t] = 1/alpha~_t[0]
  __shared__ __align__(16) float red[NN];      // rowsum, then reduction scratch

  const float* emB = emis + (size_t)b * TT * NN;  // uniform batch base
  float* outb      = out  + (size_t)b * TT * NN;  // uniform batch base

  // ---- issue early global loads (prior, em[0..5]) ----
  float2 pr2 = *(const float2*)(prior + n0);
  float2 em0 = *(const float2*)(emB + n0);
  float2 e1  = *(const float2*)(emB + 1 * NN + n0);
  float2 e2  = *(const float2*)(emB + 2 * NN + n0);
  float2 e3  = *(const float2*)(emB + 3 * NN + n0);
  float2 e4  = *(const float2*)(emB + 4 * NN + n0);
  float2 e5  = *(const float2*)(emB + 5 * NN + n0);
  pr2.x = fmaxf(pr2.x, EPSC); pr2.y = fmaxf(pr2.y, EPSC);

  // ---- row sums of clipped transition ----
  if (tid < NN) {
    const float4* row = (const float4*)(trans + tid * NN);
    float s = 0.f;
    #pragma unroll 8
    for (int j = 0; j < NN / 4; ++j) {
      float4 v = row[j];
      s += fmaxf(v.x, EPSC) + fmaxf(v.y, EPSC) + fmaxf(v.z, EPSC) + fmaxf(v.w, EPSC);
    }
    red[tid] = s;
  }
  __syncthreads();

  // ---- forward fragment (pk-packed): tf2[s][2i+(c>>1)][c&1] = Tn[p][n0+s], p=4(k+4i)+c ----
  v2f tf2[2][16];
  #pragma unroll
  for (int i = 0; i < 8; ++i) {
    #pragma unroll
    for (int c = 0; c < 4; ++c) {
      const int p = 4 * (k + 4 * i) + c;
      const float2 tv = *(const float2*)(trans + p * NN + n0);
      const float rp = red[p];
      tf2[0][2*i + (c >> 1)][c & 1] = fmaxf(tv.x, EPSC) / rp;
      tf2[1][2*i + (c >> 1)][c & 1] = fmaxf(tv.y, EPSC) / rp;
    }
  }
  // ---- backward fragment: tb2[s][...] = Tn[n0+s][4(k+4i)+c] ----
  v2f tb2[2][16];
  #pragma unroll
  for (int s = 0; s < 2; ++s) {
    const float inv = 1.0f / red[n0 + s];
    const float4* rr = (const float4*)(trans + (n0 + s) * NN);
    #pragma unroll
    for (int i = 0; i < 8; ++i) {
      const float4 tv = rr[k + 4 * i];
      tb2[s][2*i+0][0] = fmaxf(tv.x, EPSC) * inv;
      tb2[s][2*i+0][1] = fmaxf(tv.y, EPSC) * inv;
      tb2[s][2*i+1][0] = fmaxf(tv.z, EPSC) * inv;
      tb2[s][2*i+1][1] = fmaxf(tv.w, EPSC) * inv;
    }
  }

  // ---- prior normalization ----
  float vv = (k == 0) ? (pr2.x + pr2.y) : 0.f;
  #pragma unroll
  for (int m = 1; m < 64; m <<= 1) vv += __shfl_xor(vv, m, 64);
  __syncthreads();                 // all tf/tb reads of red[] complete
  if (lane == 0) red[w] = vv;
  __syncthreads();
  const float psum = (red[0] + red[1]) + (red[2] + red[3]);

  // ---- u0 = alpha~_0 ----
  float an0 = (pr2.x / psum) * __expf(em0.x);
  float an1 = (pr2.y / psum) * __expf(em0.y);
  if (k == 0) {
    float2 a2v = make_float2(an0, an1);
    *(float2*)&ubuf[0][n0] = a2v;
    *(float2*)(outb + n0) = a2v;
  }
  float dc0 = __expf(e1.x), dc1 = __expf(e1.y);  // d_1
  // Emission ring: slot m&3 holds em[m]; entering step t slots hold em[t+1..t+4].
  float2 rg0 = e4, rg1 = e5, rg2 = e2, rg3 = e3;
  BAR();                           // publish ubuf[0]

  // ================= forward =================
  // Invariant entering step t: dc = d_t; slot (t+1)&3 holds em[t+1].
  // Body consumes slot (t+1)&3 (exp -> d_{t+1}) then refills it with
  // em[t+5] (same slot index; 4 steps of slack before consumption).
  auto fstep = [&](const float* rb, float* wb, int t, float2& slot) {
    const float r0 = rb[0];                       // broadcast read, lands early
    const float4* rb4 = (const float4*)rb;
    float4 a4[8];
    #pragma unroll
    for (int i = 0; i < 8; ++i) a4[i] = rb4[k + 4 * i];
    const v2f* av = (const v2f*)a4;               // alias, no repack movs
    float z0 = dotpk16(av, tf2[0]);
    float z1 = dotpk16(av, tf2[1]);
    z0 += qswap1(z0); z0 += qswap2(z0);
    z1 += qswap1(z1); z1 += qswap2(z1);
    const float rinv = rcp_fast(r0);              // 1 instr; consistent scale
    an0 = (dc0 * rinv) * z0;
    an1 = (dc1 * rinv) * z1;
    dc0 = __expf(slot.x); dc1 = __expf(slot.y);   // d_{t+1}, off-chain
    const int tpre = (t + 5 < TT) ? (t + 5) : (TT - 1);
    const float* erow = emB + (size_t)tpre * NN;  // uniform row base (SALU)
    slot = *(const float2*)(erow + n0);           // em[t+5], slack 4 steps
    if (k == 0) {
      float2 a2v = make_float2(an0, an1);
      *(float2*)(wb + n0) = a2v;
      if (t < TT - 1) {
        float* orow = outb + (size_t)t * NN;      // uniform row base (SALU)
        *(float2*)(orow + n0) = a2v;              // stash
      }
    }
    if (tid == 0) sarr[t - 1] = rinv;             // r_{t-1}
    BAR();
  };

  fstep(ubuf[0], ubuf[1], 1, rg2);                // peel t=1,2,3
  fstep(ubuf[1], ubuf[0], 2, rg3);
  fstep(ubuf[0], ubuf[1], 3, rg0);
  for (int t = 4; t < TT; t += 4) {
    fstep(ubuf[1], ubuf[0], t + 0, rg1);
    fstep(ubuf[0], ubuf[1], t + 1, rg2);
    fstep(ubuf[1], ubuf[0], t + 2, rg3);
    fstep(ubuf[0], ubuf[1], t + 3, rg0);
  }
  const float dl0 = dc0, dl1 = dc1;               // = d_{T-1} (clamped ring)

  // ================= final softmax =================
  float v2 = (k == 0) ? (an0 + an1) : 0.f;
  #pragma unroll
  for (int m = 1; m < 64; m <<= 1) v2 += __shfl_xor(v2, m, 64);
  if (lane == 0) red[w] = v2;
  __syncthreads();
  const float total = (red[0] + red[1]) + (red[2] + red[3]);
  const float itot = 1.0f / total;
  float pc0 = an0 * itot, pc1 = an1 * itot;
  if (k == 0) *(float2*)(outb + (size_t)(TT - 1) * NN + n0) = make_float2(pc0, pc1);

  // One-time drain: forward alpha-stash stores must be visible before the
  // backward pass re-reads them (same-wave vmem ops are not address-ordered).
  asm volatile("s_waitcnt vmcnt(0)" ::: "memory");

  // ---- backward rings: slot m&3 holds em[m] / alpha~[m] ----
  float2 eb2 = *(const float2*)(emB  + (size_t)510 * NN + n0);  // em[510] -> slot 2
  float2 eb1 = *(const float2*)(emB  + (size_t)509 * NN + n0);
  float2 eb0 = *(const float2*)(emB  + (size_t)508 * NN + n0);
  float2 eb3 = *(const float2*)(emB  + (size_t)507 * NN + n0);
  float2 ac2 = *(const float2*)(outb + (size_t)510 * NN + n0);  // alpha~[510]
  float2 ac1 = *(const float2*)(outb + (size_t)509 * NN + n0);
  float2 ac0 = *(const float2*)(outb + (size_t)508 * NN + n0);
  float2 ac3 = *(const float2*)(outb + (size_t)507 * NN + n0);
  const float sl = sarr[TT - 2];
  float g0 = dl0 * sl * rcp_fast(fmaxf(an0, TINY));  // g_{T-2}
  float g1 = dl1 * sl * rcp_fast(fmaxf(an1, TINY));

  // ================= backward =================
  // Invariant entering step t: pc = p_{t+1}, g = g_t, em-slot t&3 = em[t],
  // ec-slot t&3 = alpha~_t. Body consumes both slots then refills with
  // index t-4 (same slot; 4 steps of slack).
  auto bstep = [&](float* xb, int t, float2& em_s, float2& ec_s) {
    if (k == 0) *(float2*)(xb + n0) = make_float2(pc0 * g0, pc1 * g1);
    const float sr = sarr[(t > 0) ? (t - 1) : 0];
    const float at0 = ec_s.x, at1 = ec_s.y;       // alpha~_t
    const float gn0 = __expf(em_s.x) * sr * rcp_fast(fmaxf(at0, TINY));  // g_{t-1}
    const float gn1 = __expf(em_s.y) * sr * rcp_fast(fmaxf(at1, TINY));
    const int tp4 = (t >= 4) ? (t - 4) : 0;
    const float* erow = emB  + (size_t)tp4 * NN;  // uniform row bases (SALU)
    const float* arow = outb + (size_t)tp4 * NN;
    em_s = *(const float2*)(erow + n0);           // em[t-4]
    ec_s = *(const float2*)(arow + n0);           // alpha~[t-4]
    BAR();
    const float4* qb4 = (const float4*)xb;
    float4 a4[8];
    #pragma unroll
    for (int i = 0; i < 8; ++i) a4[i] = qb4[k + 4 * i];
    const v2f* av = (const v2f*)a4;               // alias, no repack movs
    float z0 = dotpk16(av, tb2[0]);
    float z1 = dotpk16(av, tb2[1]);
    z0 += qswap1(z0); z0 += qswap2(z0);
    z1 += qswap1(z1); z1 += qswap2(z1);
    pc0 = at0 * z0;                               // p_t
    pc1 = at1 * z1;
    if (k == 0) {
      float* orow = outb + (size_t)t * NN;        // uniform row base (SALU)
      *(float2*)(orow + n0) = make_float2(pc0, pc1);
    }
    g0 = gn0; g1 = gn1;
  };

  bstep(ubuf[0], 510, eb2, ac2);                  // peel t=510,509,508
  bstep(ubuf[1], 509, eb1, ac1);
  bstep(ubuf[0], 508, eb0, ac0);
  for (int t = 507; t >= 3; t -= 4) {
    bstep(ubuf[1], t - 0, eb3, ac3);
    bstep(ubuf[0], t - 1, eb2, ac2);
    bstep(ubuf[1], t - 2, eb1, ac1);
    bstep(ubuf[0], t - 3, eb0, ac0);
  }
}

extern "C" void kernel_launch(void* const* d_in, const int* in_sizes, int n_in,
                              void* d_out, int out_size, void* d_ws, size_t ws_size,
                              hipStream_t stream) {
  (void)in_sizes; (void)n_in; (void)d_ws; (void)ws_size; (void)out_size;
  const float* trans = (const float*)d_in[0];
  const float* emis  = (const float*)d_in[1];
  const float* prior = (const float*)d_in[2];
  float* out = (float*)d_out;
  soft_viterbi_kernel<<<dim3(BB), dim3(256), 0, stream>>>(trans, emis, prior, out);
}